// Round 4
// baseline (36679.770 us; speedup 1.0000x reference)
//
#include <hip/hip_runtime.h>
#include <hip/hip_bf16.h>

#define EPSF 1e-5f

typedef unsigned short u16;
typedef unsigned int   u32;
typedef __attribute__((ext_vector_type(8))) short short8;
typedef __attribute__((ext_vector_type(4))) float f32x4;

constexpr int B  = 256;
constexpr int T  = 128;
constexpr int H  = 1024;
constexpr int INNER = 3 * H;   // 3072
constexpr int BT = B * T;      // 32768
constexpr int NZ = 2 * H;      // 2048

__device__ inline u16 f2bf(float v) {
    u32 u = __float_as_uint(v);
    return (u16)((u + 0x7fffu + ((u >> 16) & 1u)) >> 16);
}
__device__ inline float bf2f(u16 h) { return __uint_as_float(((u32)h) << 16); }

__device__ inline float fast_tanh(float x) {
    x = fminf(fmaxf(x, -15.f), 15.f);
    float e = __expf(2.f * x);
    return (e - 1.f) / (e + 1.f);
}

// ---------- one-time: transpose fp32 [1024][3072] -> split bf16 [3072][1024] ----------
__global__ __launch_bounds__(256)
void transpose_split(const float* __restrict__ src, u16* __restrict__ dhi, u16* __restrict__ dlo)
{
    __shared__ float tile[32][33];
    const int tx = threadIdx.x & 31, ty = threadIdx.x >> 5;
    const int bx = blockIdx.x, by = blockIdx.y;
    #pragma unroll
    for (int i = 0; i < 4; ++i)
        tile[ty + i * 8][tx] = src[(size_t)(by * 32 + ty + i * 8) * INNER + bx * 32 + tx];
    __syncthreads();
    #pragma unroll
    for (int i = 0; i < 4; ++i) {
        int n = bx * 32 + ty + i * 8;
        int k = by * 32 + tx;
        float v = tile[tx][ty + i * 8];
        u16 hi = f2bf(v);
        dhi[(size_t)n * H + k] = hi;
        dlo[(size_t)n * H + k] = f2bf(v - bf2f(hi));
    }
}

// ---------- split-bf16 MFMA GEMM (big x@W only): C = A[M][K] * B^T[N][K] ----------
template<int BM, int BN, int FM, int FN, bool AF32>
__global__ __launch_bounds__(256)
void gemm_mfma(const float* __restrict__ Af,
               const u16* __restrict__ Ahi, const u16* __restrict__ Alo, int lda,
               const u16* __restrict__ Bhi, const u16* __restrict__ Blo, int ldb,
               float* __restrict__ C, int ldc, int K)
{
    constexpr int NWN = BN / (FN * 16);
    constexpr int NWM = BM / (FM * 16);
    static_assert(NWM * NWN == 4, "need 4 waves");
    __shared__ char lds[(BM + BN) * 256];
    char* sAhi = lds;
    char* sAlo = lds + BM * 128;
    char* sBhi = lds + BM * 256;
    char* sBlo = lds + BM * 256 + BN * 128;

    const int tid = threadIdx.x;
    const int m0 = blockIdx.y * BM, n0 = blockIdx.x * BN;
    const int wid = tid >> 6, lane = tid & 63;
    const int wm = wid / NWN, wn = wid % NWN;
    const int lr = lane & 15, kg = lane >> 4;

    f32x4 acc[FM][FN] = {};

    for (int k0 = 0; k0 < K; k0 += 64) {
        if constexpr (AF32) {
            constexpr int NC = BM * 16 / 256;
            #pragma unroll
            for (int i = 0; i < NC; ++i) {
                int c = tid + i * 256;
                int row = c >> 4, kc = c & 15;
                const float4 v = *(const float4*)(Af + (size_t)(m0 + row) * lda + k0 + kc * 4);
                u16 h0 = f2bf(v.x), h1 = f2bf(v.y), h2 = f2bf(v.z), h3 = f2bf(v.w);
                u16 l0 = f2bf(v.x - bf2f(h0)), l1 = f2bf(v.y - bf2f(h1));
                u16 l2 = f2bf(v.z - bf2f(h2)), l3 = f2bf(v.w - bf2f(h3));
                uint2 hp, lp;
                hp.x = (u32)h0 | ((u32)h1 << 16); hp.y = (u32)h2 | ((u32)h3 << 16);
                lp.x = (u32)l0 | ((u32)l1 << 16); lp.y = (u32)l2 | ((u32)l3 << 16);
                int boff = row * 128 + ((((kc >> 1)) ^ (row & 7)) << 4) + ((kc & 1) << 3);
                *(uint2*)(sAhi + boff) = hp;
                *(uint2*)(sAlo + boff) = lp;
            }
        } else {
            constexpr int NC = BM * 8 / 256;
            #pragma unroll
            for (int i = 0; i < NC; ++i) {
                int c = tid + i * 256;
                int row = c >> 3, kc = c & 7;
                int boff = row * 128 + ((kc ^ (row & 7)) << 4);
                *(float4*)(sAhi + boff) = *(const float4*)(Ahi + (size_t)(m0 + row) * lda + k0 + kc * 8);
                *(float4*)(sAlo + boff) = *(const float4*)(Alo + (size_t)(m0 + row) * lda + k0 + kc * 8);
            }
        }
        {
            constexpr int NC = BN * 8 / 256;
            #pragma unroll
            for (int i = 0; i < NC; ++i) {
                int c = tid + i * 256;
                int row = c >> 3, kc = c & 7;
                int boff = row * 128 + ((kc ^ (row & 7)) << 4);
                *(float4*)(sBhi + boff) = *(const float4*)(Bhi + (size_t)(n0 + row) * ldb + k0 + kc * 8);
                *(float4*)(sBlo + boff) = *(const float4*)(Blo + (size_t)(n0 + row) * ldb + k0 + kc * 8);
            }
        }
        __syncthreads();

        #pragma unroll
        for (int ks = 0; ks < 2; ++ks) {
            short8 ah[FM], al[FM], bh[FN], bl[FN];
            #pragma unroll
            for (int mi = 0; mi < FM; ++mi) {
                int row = wm * FM * 16 + mi * 16 + lr;
                int off = row * 128 + ((((ks << 2) | kg) ^ (row & 7)) << 4);
                ah[mi] = *(const short8*)(sAhi + off);
                al[mi] = *(const short8*)(sAlo + off);
            }
            #pragma unroll
            for (int ni = 0; ni < FN; ++ni) {
                int row = wn * FN * 16 + ni * 16 + lr;
                int off = row * 128 + ((((ks << 2) | kg) ^ (row & 7)) << 4);
                bh[ni] = *(const short8*)(sBhi + off);
                bl[ni] = *(const short8*)(sBlo + off);
            }
            #pragma unroll
            for (int mi = 0; mi < FM; ++mi)
                #pragma unroll
                for (int ni = 0; ni < FN; ++ni) {
                    acc[mi][ni] = __builtin_amdgcn_mfma_f32_16x16x32_bf16(ah[mi], bh[ni], acc[mi][ni], 0, 0, 0);
                    acc[mi][ni] = __builtin_amdgcn_mfma_f32_16x16x32_bf16(ah[mi], bl[ni], acc[mi][ni], 0, 0, 0);
                    acc[mi][ni] = __builtin_amdgcn_mfma_f32_16x16x32_bf16(al[mi], bh[ni], acc[mi][ni], 0, 0, 0);
                }
        }
        __syncthreads();
    }

    #pragma unroll
    for (int mi = 0; mi < FM; ++mi)
        #pragma unroll
        for (int ni = 0; ni < FN; ++ni) {
            int col = n0 + wn * FN * 16 + ni * 16 + lr;
            #pragma unroll
            for (int r = 0; r < 4; ++r) {
                int row = m0 + wm * FM * 16 + mi * 16 + kg * 4 + r;
                C[(size_t)row * ldc + col] = acc[mi][ni][r];
            }
        }
}

// ---------- block reduce (sum, sumsq) over 256 threads ----------
__device__ inline void block_reduce2(float& s, float& sq, int tid) {
    #pragma unroll
    for (int off = 32; off > 0; off >>= 1) { s += __shfl_down(s, off); sq += __shfl_down(sq, off); }
    __shared__ float rs[4], rq[4];
    if ((tid & 63) == 0) { rs[tid >> 6] = s; rq[tid >> 6] = sq; }
    __syncthreads();
    s  = rs[0] + rs[1] + rs[2] + rs[3];
    sq = rq[0] + rq[1] + rq[2] + rq[3];
}

// ---------- LN over S1 rows of 3072 (adds bias first), in place, gamma0/beta0 ----------
__global__ __launch_bounds__(256)
void ln_rows_v(float* __restrict__ S1, const float* __restrict__ bias,
               const float* __restrict__ gammas, const float* __restrict__ betas)
{
    const int row = blockIdx.x, tid = threadIdx.x;
    float* p = S1 + (size_t)row * INNER;
    float a[12];
    float s = 0.f, sq = 0.f;
    #pragma unroll
    for (int i = 0; i < 3; ++i) {
        int c = tid + i * 256;
        float4 v = *(const float4*)(p + c * 4);
        float4 bb = *(const float4*)(bias + c * 4);
        a[i*4+0] = v.x + bb.x; a[i*4+1] = v.y + bb.y; a[i*4+2] = v.z + bb.z; a[i*4+3] = v.w + bb.w;
        s += a[i*4+0] + a[i*4+1] + a[i*4+2] + a[i*4+3];
        sq += a[i*4+0]*a[i*4+0] + a[i*4+1]*a[i*4+1] + a[i*4+2]*a[i*4+2] + a[i*4+3]*a[i*4+3];
    }
    block_reduce2(s, sq, tid);
    const float mean = s / (float)INNER;
    const float var  = sq / (float)INNER - mean * mean;
    const float denom = sqrtf(var + EPSF) + EPSF;
    #pragma unroll
    for (int i = 0; i < 3; ++i) {
        int c = tid + i * 256;
        float4 o;
        o.x = gammas[c*4+0] * (a[i*4+0] - mean) / denom + betas[c*4+0];
        o.y = gammas[c*4+1] * (a[i*4+1] - mean) / denom + betas[c*4+1];
        o.z = gammas[c*4+2] * (a[i*4+2] - mean) / denom + betas[c*4+2];
        o.w = gammas[c*4+3] * (a[i*4+3] - mean) / denom + betas[c*4+3];
        *(float4*)(p + c * 4) = o;
    }
}

// ================= step kernel A: fused e2(t-1) + GEMM1 (hcur @ Uzr^T -> s2raw) =================
// grid (NZ/64=32, B/64=4), 256 threads, tile 64x64.
template<bool PRO>
__global__ __launch_bounds__(256)
void stepA(const float* __restrict__ hprev, float* __restrict__ hcur,
           const float* __restrict__ z, const float* __restrict__ candraw,
           const float* __restrict__ S1,
           const float* __restrict__ gammas, const float* __restrict__ betas,
           const u16* __restrict__ Bhi, const u16* __restrict__ Blo,
           float* __restrict__ s2raw, float* __restrict__ out, int t)
{
    constexpr int BM = 64, BN = 64, FM = 2, FN = 2;
    __shared__ char lds[(BM + BN) * 256];
    char* sAhi = lds;
    char* sAlo = lds + BM * 128;
    char* sBhi = lds + BM * 256;
    char* sBlo = lds + BM * 256 + BN * 128;

    const int tid = threadIdx.x;
    const int m0 = blockIdx.y * BM, n0 = blockIdx.x * BN;

    if constexpr (PRO) {
        // e2 of step t-1 for my 64 rows (redundant across n-blocks; identical values)
        const int row = m0 + (tid >> 2), q = tid & 3;
        const float* crow = candraw + (size_t)row * H + q * 256;
        float s = 0.f, sq = 0.f;
        for (int i = 0; i < 64; ++i) {
            float4 v = *(const float4*)(crow + i * 4);
            s += v.x + v.y + v.z + v.w;
            sq += v.x*v.x + v.y*v.y + v.z*v.z + v.w*v.w;
        }
        s += __shfl_xor(s, 1); sq += __shfl_xor(sq, 1);
        s += __shfl_xor(s, 2); sq += __shfl_xor(sq, 2);
        const float mean = s * (1.f / 1024.f);
        const float var  = sq * (1.f / 1024.f) - mean * mean;
        const float denom = sqrtf(var + EPSF) + EPSF;

        const float* s1c = S1 + ((size_t)row * T + (t - 1)) * INNER + NZ + q * 256;
        const float* gm  = gammas + INNER + NZ + q * 256;
        const float* bt  = betas  + INNER + NZ + q * 256;
        const float* zr  = z     + (size_t)row * H + q * 256;
        const float* hp  = hprev + (size_t)row * H + q * 256;
        float*       hc  = hcur  + (size_t)row * H + q * 256;
        float*       op  = out + ((size_t)row * T + (t - 1)) * H + q * 256;
        for (int i = 0; i < 64; ++i) {
            float4 v  = *(const float4*)(crow + i * 4);
            float4 sv = *(const float4*)(s1c + i * 4);
            float4 gv = *(const float4*)(gm + i * 4);
            float4 bv = *(const float4*)(bt + i * 4);
            float4 zv = *(const float4*)(zr + i * 4);
            float4 hv = *(const float4*)(hp + i * 4);
            float4 o;
            o.x = zv.x * hv.x + (1.f - zv.x) * fast_tanh(sv.x + gv.x * (v.x - mean) / denom + bv.x);
            o.y = zv.y * hv.y + (1.f - zv.y) * fast_tanh(sv.y + gv.y * (v.y - mean) / denom + bv.y);
            o.z = zv.z * hv.z + (1.f - zv.z) * fast_tanh(sv.z + gv.z * (v.z - mean) / denom + bv.z);
            o.w = zv.w * hv.w + (1.f - zv.w) * fast_tanh(sv.w + gv.w * (v.w - mean) / denom + bv.w);
            *(float4*)(hc + i * 4) = o;
            if (n0 == 0) *(float4*)(op + i * 4) = o;
        }
        __threadfence();
        __syncthreads();
    }

    // GEMM: s2raw tile = hcur[m0:m0+64] @ Uzr^T[n0:n0+64], 3-pass split
    const int wid = tid >> 6, lane = tid & 63;
    const int wm = wid >> 1, wn = wid & 1;
    const int lr = lane & 15, kg = lane >> 4;
    f32x4 acc[FM][FN] = {};

    for (int k0 = 0; k0 < H; k0 += 64) {
        #pragma unroll
        for (int i = 0; i < 4; ++i) {
            int c = tid + i * 256;
            int row = c >> 4, kc = c & 15;
            const float4 v = *(const float4*)(hcur + (size_t)(m0 + row) * H + k0 + kc * 4);
            u16 h0 = f2bf(v.x), h1 = f2bf(v.y), h2 = f2bf(v.z), h3 = f2bf(v.w);
            u16 l0 = f2bf(v.x - bf2f(h0)), l1 = f2bf(v.y - bf2f(h1));
            u16 l2 = f2bf(v.z - bf2f(h2)), l3 = f2bf(v.w - bf2f(h3));
            uint2 hpk, lpk;
            hpk.x = (u32)h0 | ((u32)h1 << 16); hpk.y = (u32)h2 | ((u32)h3 << 16);
            lpk.x = (u32)l0 | ((u32)l1 << 16); lpk.y = (u32)l2 | ((u32)l3 << 16);
            int boff = row * 128 + ((((kc >> 1)) ^ (row & 7)) << 4) + ((kc & 1) << 3);
            *(uint2*)(sAhi + boff) = hpk;
            *(uint2*)(sAlo + boff) = lpk;
        }
        #pragma unroll
        for (int i = 0; i < 2; ++i) {
            int c = tid + i * 256;
            int row = c >> 3, kc = c & 7;
            int boff = row * 128 + ((kc ^ (row & 7)) << 4);
            *(float4*)(sBhi + boff) = *(const float4*)(Bhi + (size_t)(n0 + row) * H + k0 + kc * 8);
            *(float4*)(sBlo + boff) = *(const float4*)(Blo + (size_t)(n0 + row) * H + k0 + kc * 8);
        }
        __syncthreads();

        #pragma unroll
        for (int ks = 0; ks < 2; ++ks) {
            short8 ah[FM], al[FM], bh[FN], bl[FN];
            #pragma unroll
            for (int mi = 0; mi < FM; ++mi) {
                int row = wm * 32 + mi * 16 + lr;
                int off = row * 128 + ((((ks << 2) | kg) ^ (row & 7)) << 4);
                ah[mi] = *(const short8*)(sAhi + off);
                al[mi] = *(const short8*)(sAlo + off);
            }
            #pragma unroll
            for (int ni = 0; ni < FN; ++ni) {
                int row = wn * 32 + ni * 16 + lr;
                int off = row * 128 + ((((ks << 2) | kg) ^ (row & 7)) << 4);
                bh[ni] = *(const short8*)(sBhi + off);
                bl[ni] = *(const short8*)(sBlo + off);
            }
            #pragma unroll
            for (int mi = 0; mi < FM; ++mi)
                #pragma unroll
                for (int ni = 0; ni < FN; ++ni) {
                    acc[mi][ni] = __builtin_amdgcn_mfma_f32_16x16x32_bf16(ah[mi], bh[ni], acc[mi][ni], 0, 0, 0);
                    acc[mi][ni] = __builtin_amdgcn_mfma_f32_16x16x32_bf16(ah[mi], bl[ni], acc[mi][ni], 0, 0, 0);
                    acc[mi][ni] = __builtin_amdgcn_mfma_f32_16x16x32_bf16(al[mi], bh[ni], acc[mi][ni], 0, 0, 0);
                }
        }
        __syncthreads();
    }

    #pragma unroll
    for (int mi = 0; mi < FM; ++mi)
        #pragma unroll
        for (int ni = 0; ni < FN; ++ni) {
            int col = n0 + wn * 32 + ni * 16 + lr;
            #pragma unroll
            for (int r = 0; r < 4; ++r) {
                int row = m0 + wm * 32 + mi * 16 + kg * 4 + r;
                s2raw[(size_t)row * NZ + col] = acc[mi][ni][r];
            }
        }
}

// ================= step kernel B: fused e1 + GEMM2 (rh @ Uc^T -> candraw) =================
// grid (H/64=16, B/32=8), 256 threads, tile 32x64.
__global__ __launch_bounds__(256)
void stepB(const float* __restrict__ hcur, const float* __restrict__ s2raw,
           float* __restrict__ zout, float* __restrict__ rh,
           const float* __restrict__ S1,
           const float* __restrict__ gammas, const float* __restrict__ betas,
           const u16* __restrict__ Bhi, const u16* __restrict__ Blo,
           float* __restrict__ candraw, int t)
{
    constexpr int BM = 32, BN = 64, FM = 1, FN = 2;
    __shared__ char lds[(BM + BN) * 256];
    char* sAhi = lds;
    char* sAlo = lds + BM * 128;
    char* sBhi = lds + BM * 256;
    char* sBlo = lds + BM * 256 + BN * 128;

    const int tid = threadIdx.x;
    const int m0 = blockIdx.y * BM, n0 = blockIdx.x * BN;

    {
        // e1 for my 32 rows (redundant across n-blocks; identical values)
        const int row = m0 + (tid >> 3), q = tid & 7;
        const float* srow = s2raw + (size_t)row * NZ + q * 256;
        float s = 0.f, sq = 0.f;
        for (int i = 0; i < 64; ++i) {
            float4 v = *(const float4*)(srow + i * 4);
            s += v.x + v.y + v.z + v.w;
            sq += v.x*v.x + v.y*v.y + v.z*v.z + v.w*v.w;
        }
        s += __shfl_xor(s, 1); sq += __shfl_xor(sq, 1);
        s += __shfl_xor(s, 2); sq += __shfl_xor(sq, 2);
        s += __shfl_xor(s, 4); sq += __shfl_xor(sq, 4);
        const float mean = s * (1.f / 2048.f);
        const float var  = sq * (1.f / 2048.f) - mean * mean;
        const float denom = sqrtf(var + EPSF) + EPSF;

        const int c0 = q * 256;
        const float* s1 = S1 + ((size_t)row * T + t) * INNER + c0;
        const float* gm = gammas + INNER + c0;
        const float* bt = betas  + INNER + c0;
        if (q < 4) {
            if (n0 == 0) {
                float* zp = zout + (size_t)row * H + c0;
                for (int i = 0; i < 64; ++i) {
                    float4 v  = *(const float4*)(srow + i * 4);
                    float4 sv = *(const float4*)(s1 + i * 4);
                    float4 gv = *(const float4*)(gm + i * 4);
                    float4 bv = *(const float4*)(bt + i * 4);
                    float4 o;
                    o.x = fminf(fmaxf(0.2f * (sv.x + gv.x * (v.x - mean) / denom + bv.x) + 0.5f, 0.f), 1.f);
                    o.y = fminf(fmaxf(0.2f * (sv.y + gv.y * (v.y - mean) / denom + bv.y) + 0.5f, 0.f), 1.f);
                    o.z = fminf(fmaxf(0.2f * (sv.z + gv.z * (v.z - mean) / denom + bv.z) + 0.5f, 0.f), 1.f);
                    o.w = fminf(fmaxf(0.2f * (sv.w + gv.w * (v.w - mean) / denom + bv.w) + 0.5f, 0.f), 1.f);
                    *(float4*)(zp + i * 4) = o;
                }
            }
        } else {
            const float* hp = hcur + (size_t)row * H + (c0 - 1024);
            float* rp = rh + (size_t)row * H + (c0 - 1024);
            for (int i = 0; i < 64; ++i) {
                float4 v  = *(const float4*)(srow + i * 4);
                float4 sv = *(const float4*)(s1 + i * 4);
                float4 gv = *(const float4*)(gm + i * 4);
                float4 bv = *(const float4*)(bt + i * 4);
                float4 hv = *(const float4*)(hp + i * 4);
                float4 o;
                o.x = fminf(fmaxf(0.2f * (sv.x + gv.x * (v.x - mean) / denom + bv.x) + 0.5f, 0.f), 1.f) * hv.x;
                o.y = fminf(fmaxf(0.2f * (sv.y + gv.y * (v.y - mean) / denom + bv.y) + 0.5f, 0.f), 1.f) * hv.y;
                o.z = fminf(fmaxf(0.2f * (sv.z + gv.z * (v.z - mean) / denom + bv.z) + 0.5f, 0.f), 1.f) * hv.z;
                o.w = fminf(fmaxf(0.2f * (sv.w + gv.w * (v.w - mean) / denom + bv.w) + 0.5f, 0.f), 1.f) * hv.w;
                *(float4*)(rp + i * 4) = o;
            }
        }
        __threadfence();
        __syncthreads();
    }

    // GEMM: candraw tile = rh[m0:m0+32] @ Uc^T[n0:n0+64]
    const int wid = tid >> 6, lane = tid & 63;
    const int wm = wid >> 1, wn = wid & 1;
    const int lr = lane & 15, kg = lane >> 4;
    f32x4 acc[FM][FN] = {};

    for (int k0 = 0; k0 < H; k0 += 64) {
        #pragma unroll
        for (int i = 0; i < 2; ++i) {
            int c = tid + i * 256;
            int row = c >> 4, kc = c & 15;
            const float4 v = *(const float4*)(rh + (size_t)(m0 + row) * H + k0 + kc * 4);
            u16 h0 = f2bf(v.x), h1 = f2bf(v.y), h2 = f2bf(v.z), h3 = f2bf(v.w);
            u16 l0 = f2bf(v.x - bf2f(h0)), l1 = f2bf(v.y - bf2f(h1));
            u16 l2 = f2bf(v.z - bf2f(h2)), l3 = f2bf(v.w - bf2f(h3));
            uint2 hpk, lpk;
            hpk.x = (u32)h0 | ((u32)h1 << 16); hpk.y = (u32)h2 | ((u32)h3 << 16);
            lpk.x = (u32)l0 | ((u32)l1 << 16); lpk.y = (u32)l2 | ((u32)l3 << 16);
            int boff = row * 128 + ((((kc >> 1)) ^ (row & 7)) << 4) + ((kc & 1) << 3);
            *(uint2*)(sAhi + boff) = hpk;
            *(uint2*)(sAlo + boff) = lpk;
        }
        #pragma unroll
        for (int i = 0; i < 2; ++i) {
            int c = tid + i * 256;
            int row = c >> 3, kc = c & 7;
            int boff = row * 128 + ((kc ^ (row & 7)) << 4);
            *(float4*)(sBhi + boff) = *(const float4*)(Bhi + (size_t)(n0 + row) * H + k0 + kc * 8);
            *(float4*)(sBlo + boff) = *(const float4*)(Blo + (size_t)(n0 + row) * H + k0 + kc * 8);
        }
        __syncthreads();

        #pragma unroll
        for (int ks = 0; ks < 2; ++ks) {
            short8 ah[FM], al[FM], bh[FN], bl[FN];
            {
                int row = wm * 16 + lr;
                int off = row * 128 + ((((ks << 2) | kg) ^ (row & 7)) << 4);
                ah[0] = *(const short8*)(sAhi + off);
                al[0] = *(const short8*)(sAlo + off);
            }
            #pragma unroll
            for (int ni = 0; ni < FN; ++ni) {
                int row = wn * 32 + ni * 16 + lr;
                int off = row * 128 + ((((ks << 2) | kg) ^ (row & 7)) << 4);
                bh[ni] = *(const short8*)(sBhi + off);
                bl[ni] = *(const short8*)(sBlo + off);
            }
            #pragma unroll
            for (int ni = 0; ni < FN; ++ni) {
                acc[0][ni] = __builtin_amdgcn_mfma_f32_16x16x32_bf16(ah[0], bh[ni], acc[0][ni], 0, 0, 0);
                acc[0][ni] = __builtin_amdgcn_mfma_f32_16x16x32_bf16(ah[0], bl[ni], acc[0][ni], 0, 0, 0);
                acc[0][ni] = __builtin_amdgcn_mfma_f32_16x16x32_bf16(al[0], bh[ni], acc[0][ni], 0, 0, 0);
            }
        }
        __syncthreads();
    }

    #pragma unroll
    for (int ni = 0; ni < FN; ++ni) {
        int col = n0 + wn * 32 + ni * 16 + lr;
        #pragma unroll
        for (int r = 0; r < 4; ++r) {
            int row = m0 + wm * 16 + kg * 4 + r;
            candraw[(size_t)row * H + col] = acc[0][ni][r];
        }
    }
}

// ---------- final e2: write out[:, T-1] ----------
__global__ __launch_bounds__(256)
void final_e2(const float* __restrict__ candraw, const float* __restrict__ S1,
              const float* __restrict__ gammas, const float* __restrict__ betas,
              const float* __restrict__ z, const float* __restrict__ h,
              float* __restrict__ out)
{
    const int b = blockIdx.x, tid = threadIdx.x;
    float a[4];
    {
        float4 v = *(const float4*)(candraw + (size_t)b * H + tid * 4);
        a[0]=v.x; a[1]=v.y; a[2]=v.z; a[3]=v.w;
    }
    float s = a[0]+a[1]+a[2]+a[3];
    float sq = a[0]*a[0]+a[1]*a[1]+a[2]*a[2]+a[3]*a[3];
    block_reduce2(s, sq, tid);
    const float mean = s / (float)H;
    const float var  = sq / (float)H - mean * mean;
    const float denom = sqrtf(var + EPSF) + EPSF;

    const float* s1 = S1 + ((size_t)b * T + (T - 1)) * INNER + NZ;
    const int j0 = tid * 4;
    float4 oo; float* op = (float*)&oo;
    #pragma unroll
    for (int q = 0; q < 4; ++q) {
        int j = j0 + q;
        float ln = gammas[INNER + NZ + j] * (a[q] - mean) / denom + betas[INNER + NZ + j];
        float cand = fast_tanh(s1[j] + ln);
        float zz = z[(size_t)b * H + j];
        float hold = h[(size_t)b * H + j];
        op[q] = zz * hold + (1.f - zz) * cand;
    }
    *(float4*)(out + ((size_t)b * T + (T - 1)) * H + j0) = oo;
}

// ================= fallback (validated fp32 path) =================
__global__ __launch_bounds__(256)
void gemm_fb(const float* __restrict__ A, int lda,
             const float* __restrict__ Bm, int ldb,
             float* __restrict__ C, int ldc, int K)
{
    constexpr int BM = 64, BN = 64, BK = 16;
    __shared__ float As[BK][BM];
    __shared__ float Bs[BK][BN];
    const int tid = threadIdx.x;
    const int tx = tid & 15, ty = tid >> 4;
    float acc[4][4] = {};
    const float* Ab = A + (size_t)blockIdx.y * BM * lda;
    const float* Bb = Bm + (size_t)blockIdx.x * BN;
    for (int k0 = 0; k0 < K; k0 += BK) {
        #pragma unroll
        for (int i = 0; i < 4; ++i) {
            int e = tid + i * 256; int m = e >> 4, k = e & 15;
            As[k][m] = Ab[(size_t)m * lda + k0 + k];
        }
        #pragma unroll
        for (int i = 0; i < 4; ++i) {
            int e = tid + i * 256; int k = e >> 6, n = e & 63;
            Bs[k][n] = Bb[(size_t)(k0 + k) * ldb + n];
        }
        __syncthreads();
        #pragma unroll
        for (int k = 0; k < BK; ++k) {
            float av[4], bv[4];
            #pragma unroll
            for (int i = 0; i < 4; ++i) av[i] = As[k][ty * 4 + i];
            #pragma unroll
            for (int j = 0; j < 4; ++j) bv[j] = Bs[k][tx * 4 + j];
            #pragma unroll
            for (int i = 0; i < 4; ++i)
                #pragma unroll
                for (int j = 0; j < 4; ++j)
                    acc[i][j] = fmaf(av[i], bv[j], acc[i][j]);
        }
        __syncthreads();
    }
    const int row0 = blockIdx.y * BM + ty * 4;
    const int col0 = blockIdx.x * BN + tx * 4;
    #pragma unroll
    for (int i = 0; i < 4; ++i)
        #pragma unroll
        for (int j = 0; j < 4; ++j)
            C[(size_t)(row0 + i) * ldc + col0 + j] = acc[i][j];
}

__global__ __launch_bounds__(256)
void step_e1_fb(const float* __restrict__ s2raw, const float* __restrict__ S1,
                const float* __restrict__ h,
                const float* __restrict__ gammas, const float* __restrict__ betas,
                float* __restrict__ z, float* __restrict__ rh, int t)
{
    const int b = blockIdx.x, tid = threadIdx.x;
    const float* row = s2raw + (size_t)b * NZ;
    float v[8]; float s = 0.f, sq = 0.f;
    #pragma unroll
    for (int i = 0; i < 8; ++i) { v[i] = row[tid + i * 256]; s += v[i]; sq += v[i]*v[i]; }
    block_reduce2(s, sq, tid);
    const float mean = s / (float)NZ;
    const float var  = sq / (float)NZ - mean * mean;
    const float denom = sqrtf(var + EPSF) + EPSF;
    const float* s1 = S1 + (size_t)(b * T + t) * INNER;
    #pragma unroll
    for (int i = 0; i < 8; ++i) {
        int j = tid + i * 256;
        float ln = gammas[INNER + j] * (v[i] - mean) / denom + betas[INNER + j];
        float sv = 0.2f * (s1[j] + ln) + 0.5f;
        sv = fminf(fmaxf(sv, 0.f), 1.f);
        if (j < H) z[(size_t)b * H + j] = sv;
        else       rh[(size_t)b * H + (j - H)] = sv * h[(size_t)b * H + (j - H)];
    }
}

__global__ __launch_bounds__(256)
void step_e2_fb(const float* __restrict__ candraw, const float* __restrict__ S1,
                const float* __restrict__ gammas, const float* __restrict__ betas,
                const float* __restrict__ z, float* __restrict__ h,
                float* __restrict__ out, int t)
{
    const int b = blockIdx.x, tid = threadIdx.x;
    float v[4]; float s = 0.f, sq = 0.f;
    #pragma unroll
    for (int i = 0; i < 4; ++i) { v[i] = candraw[(size_t)b * H + tid + i * 256]; s += v[i]; sq += v[i]*v[i]; }
    block_reduce2(s, sq, tid);
    const float mean = s / (float)H;
    const float var  = sq / (float)H - mean * mean;
    const float denom = sqrtf(var + EPSF) + EPSF;
    const float* s1 = S1 + (size_t)(b * T + t) * INNER + NZ;
    #pragma unroll
    for (int i = 0; i < 4; ++i) {
        int j = tid + i * 256;
        float ln = gammas[INNER + NZ + j] * (v[i] - mean) / denom + betas[INNER + NZ + j];
        float cand = tanhf(s1[j] + ln);
        float zz = z[(size_t)b * H + j];
        float hold = h[(size_t)b * H + j];
        float hn = zz * hold + (1.f - zz) * cand;
        h[(size_t)b * H + j] = hn;
        out[((size_t)b * T + t) * H + j] = hn;
    }
}

// ================= launch =================
extern "C" void kernel_launch(void* const* d_in, const int* in_sizes, int n_in,
                              void* d_out, int out_size, void* d_ws, size_t ws_size,
                              hipStream_t stream) {
    const float* x      = (const float*)d_in[0];
    const float* W      = (const float*)d_in[1];
    const float* U      = (const float*)d_in[2];
    const float* bias   = (const float*)d_in[3];
    const float* gammas = (const float*)d_in[4];
    const float* betas  = (const float*)d_in[5];
    float* out = (float*)d_out;
    (void)in_sizes; (void)n_in; (void)out_size;

    char* ws = (char*)d_ws;
    size_t off = 0;
    auto alloc = [&](size_t bytes) { void* p = ws + off; off += (bytes + 255) & ~(size_t)255; return p; };

    const size_t sz_S1 = (size_t)BT * INNER * 4;          // 402.7 MB
    const size_t sz_T  = (size_t)INNER * H * 2;           // 6.29 MB per split half
    const size_t sz_BH = (size_t)B * H * 4;               // 1 MB
    const size_t need_new = sz_S1 + 4 * sz_T + 5 * sz_BH + (size_t)B * NZ * 4 + 16 * 1024;

    if (ws_size >= need_new) {
        float* S1    = (float*)alloc(sz_S1);
        u16* WT_hi   = (u16*)alloc(sz_T);
        u16* WT_lo   = (u16*)alloc(sz_T);
        u16* UT_hi   = (u16*)alloc(sz_T);
        u16* UT_lo   = (u16*)alloc(sz_T);
        float* hb0   = (float*)alloc(sz_BH);
        float* hb1   = (float*)alloc(sz_BH);
        float* z     = (float*)alloc(sz_BH);
        float* rh    = (float*)alloc(sz_BH);
        float* candraw = (float*)alloc(sz_BH);
        float* s2raw = (float*)alloc((size_t)B * NZ * 4);

        transpose_split<<<dim3(INNER / 32, H / 32), 256, 0, stream>>>(W, WT_hi, WT_lo);
        transpose_split<<<dim3(INNER / 32, H / 32), 256, 0, stream>>>(U, UT_hi, UT_lo);

        gemm_mfma<128, 128, 4, 4, true><<<dim3(INNER / 128, BT / 128), 256, 0, stream>>>(
            x, nullptr, nullptr, H, WT_hi, WT_lo, H, S1, INNER, H);
        ln_rows_v<<<BT, 256, 0, stream>>>(S1, bias, gammas, betas);

        hipMemsetAsync(hb0, 0, sz_BH, stream);

        const u16* Uc_hi = UT_hi + (size_t)NZ * H;
        const u16* Uc_lo = UT_lo + (size_t)NZ * H;

        for (int t = 0; t < T; ++t) {
            float* hcur = (t & 1) ? hb1 : hb0;
            float* hprev = (t & 1) ? hb0 : hb1;
            if (t == 0) {
                stepA<false><<<dim3(NZ / 64, B / 64), 256, 0, stream>>>(
                    hb0, hb0, z, candraw, S1, gammas, betas, UT_hi, UT_lo, s2raw, out, 0);
            } else {
                stepA<true><<<dim3(NZ / 64, B / 64), 256, 0, stream>>>(
                    hprev, hcur, z, candraw, S1, gammas, betas, UT_hi, UT_lo, s2raw, out, t);
            }
            stepB<<<dim3(H / 64, B / 32), 256, 0, stream>>>(
                hcur, s2raw, z, rh, S1, gammas, betas, Uc_hi, Uc_lo, candraw, t);
        }
        final_e2<<<B, 256, 0, stream>>>(candraw, S1, gammas, betas, z, hb1, out);
    } else {
        // fallback: validated fp32 path
        float* S1    = (float*)alloc(sz_S1);
        float* h     = (float*)alloc(sz_BH);
        float* z     = (float*)alloc(sz_BH);
        float* rh    = (float*)alloc(sz_BH);
        float* s2raw = (float*)alloc((size_t)B * NZ * 4);
        float* candraw = (float*)alloc(sz_BH);

        hipMemsetAsync(h, 0, sz_BH, stream);
        gemm_fb<<<dim3(INNER / 64, BT / 64), 256, 0, stream>>>(x, H, W, INNER, S1, INNER, H);
        ln_rows_v<<<BT, 256, 0, stream>>>(S1, bias, gammas, betas);
        for (int t = 0; t < T; ++t) {
            gemm_fb<<<dim3(NZ / 64, B / 64), 256, 0, stream>>>(h, H, U, INNER, s2raw, NZ, H);
            step_e1_fb<<<B, 256, 0, stream>>>(s2raw, S1, h, gammas, betas, z, rh, t);
            gemm_fb<<<dim3(H / 64, B / 64), 256, 0, stream>>>(rh, H, U + NZ, INNER, candraw, H, H);
            step_e2_fb<<<B, 256, 0, stream>>>(candraw, S1, gammas, betas, z, h, out, t);
        }
    }
}

// Round 5
// 5724.197 us; speedup vs baseline: 6.4078x; 6.4078x over previous
//
#include <hip/hip_runtime.h>
#include <hip/hip_bf16.h>

#define EPSF 1e-5f

typedef unsigned short u16;
typedef unsigned int   u32;
typedef __attribute__((ext_vector_type(8))) short short8;
typedef __attribute__((ext_vector_type(4))) float f32x4;

constexpr int B  = 256;
constexpr int T  = 128;
constexpr int H  = 1024;
constexpr int INNER = 3 * H;   // 3072
constexpr int BT = B * T;      // 32768
constexpr int NZ = 2 * H;      // 2048

__device__ inline u16 f2bf(float v) {
    u32 u = __float_as_uint(v);
    return (u16)((u + 0x7fffu + ((u >> 16) & 1u)) >> 16);
}
__device__ inline float bf2f(u16 h) { return __uint_as_float(((u32)h) << 16); }

// ---------- one-time: transpose fp32 [1024][3072] -> split bf16 [3072][1024] ----------
__global__ __launch_bounds__(256)
void transpose_split(const float* __restrict__ src, u16* __restrict__ dhi, u16* __restrict__ dlo)
{
    __shared__ float tile[32][33];
    const int tx = threadIdx.x & 31, ty = threadIdx.x >> 5;
    const int bx = blockIdx.x, by = blockIdx.y;
    #pragma unroll
    for (int i = 0; i < 4; ++i)
        tile[ty + i * 8][tx] = src[(size_t)(by * 32 + ty + i * 8) * INNER + bx * 32 + tx];
    __syncthreads();
    #pragma unroll
    for (int i = 0; i < 4; ++i) {
        int n = bx * 32 + ty + i * 8;
        int k = by * 32 + tx;
        float v = tile[tx][ty + i * 8];
        u16 hi = f2bf(v);
        dhi[(size_t)n * H + k] = hi;
        dlo[(size_t)n * H + k] = f2bf(v - bf2f(hi));
    }
}

// ---------- split-bf16 MFMA GEMM: C[M][N] fp32 = A[M][K] * B^T[N][K] ----------
// A: fp32 (converted in staging) if AF32, else pre-split bf16 hi/lo.
// B: pre-split bf16 hi/lo, [N][K] k-contiguous.
// 3 MFMA passes: hi*hi + hi*lo + lo*hi. LDS rows 128B, XOR-swizzled 16B slots.
template<int BM, int BN, int FM, int FN, bool AF32>
__global__ __launch_bounds__(256)
void gemm_mfma(const float* __restrict__ Af,
               const u16* __restrict__ Ahi, const u16* __restrict__ Alo, int lda,
               const u16* __restrict__ Bhi, const u16* __restrict__ Blo, int ldb,
               float* __restrict__ C, int ldc, int K)
{
    constexpr int NWN = BN / (FN * 16);
    constexpr int NWM = BM / (FM * 16);
    static_assert(NWM * NWN == 4, "need 4 waves");
    static_assert((BM * 8) % 256 == 0 || AF32, "A staging divisibility");
    __shared__ char lds[(BM + BN) * 256];
    char* sAhi = lds;
    char* sAlo = lds + BM * 128;
    char* sBhi = lds + BM * 256;
    char* sBlo = lds + BM * 256 + BN * 128;

    const int tid = threadIdx.x;
    const int m0 = blockIdx.y * BM, n0 = blockIdx.x * BN;
    const int wid = tid >> 6, lane = tid & 63;
    const int wm = wid / NWN, wn = wid % NWN;
    const int lr = lane & 15, kg = lane >> 4;

    f32x4 acc[FM][FN] = {};

    for (int k0 = 0; k0 < K; k0 += 64) {
        if constexpr (AF32) {
            constexpr int NC = BM * 16 / 256;
            #pragma unroll
            for (int i = 0; i < NC; ++i) {
                int c = tid + i * 256;
                int row = c >> 4, kc = c & 15;
                const float4 v = *(const float4*)(Af + (size_t)(m0 + row) * lda + k0 + kc * 4);
                u16 h0 = f2bf(v.x), h1 = f2bf(v.y), h2 = f2bf(v.z), h3 = f2bf(v.w);
                u16 l0 = f2bf(v.x - bf2f(h0)), l1 = f2bf(v.y - bf2f(h1));
                u16 l2 = f2bf(v.z - bf2f(h2)), l3 = f2bf(v.w - bf2f(h3));
                uint2 hp, lp;
                hp.x = (u32)h0 | ((u32)h1 << 16); hp.y = (u32)h2 | ((u32)h3 << 16);
                lp.x = (u32)l0 | ((u32)l1 << 16); lp.y = (u32)l2 | ((u32)l3 << 16);
                int boff = row * 128 + ((((kc >> 1)) ^ (row & 7)) << 4) + ((kc & 1) << 3);
                *(uint2*)(sAhi + boff) = hp;
                *(uint2*)(sAlo + boff) = lp;
            }
        } else {
            constexpr int NC = BM * 8 / 256;
            #pragma unroll
            for (int i = 0; i < NC; ++i) {
                int c = tid + i * 256;
                int row = c >> 3, kc = c & 7;
                int boff = row * 128 + ((kc ^ (row & 7)) << 4);
                *(float4*)(sAhi + boff) = *(const float4*)(Ahi + (size_t)(m0 + row) * lda + k0 + kc * 8);
                *(float4*)(sAlo + boff) = *(const float4*)(Alo + (size_t)(m0 + row) * lda + k0 + kc * 8);
            }
        }
        {
            constexpr int NC = BN * 8 / 256;
            #pragma unroll
            for (int i = 0; i < NC; ++i) {
                int c = tid + i * 256;
                int row = c >> 3, kc = c & 7;
                int boff = row * 128 + ((kc ^ (row & 7)) << 4);
                *(float4*)(sBhi + boff) = *(const float4*)(Bhi + (size_t)(n0 + row) * ldb + k0 + kc * 8);
                *(float4*)(sBlo + boff) = *(const float4*)(Blo + (size_t)(n0 + row) * ldb + k0 + kc * 8);
            }
        }
        __syncthreads();

        #pragma unroll
        for (int ks = 0; ks < 2; ++ks) {
            short8 ah[FM], al[FM], bh[FN], bl[FN];
            #pragma unroll
            for (int mi = 0; mi < FM; ++mi) {
                int row = wm * FM * 16 + mi * 16 + lr;
                int off = row * 128 + ((((ks << 2) | kg) ^ (row & 7)) << 4);
                ah[mi] = *(const short8*)(sAhi + off);
                al[mi] = *(const short8*)(sAlo + off);
            }
            #pragma unroll
            for (int ni = 0; ni < FN; ++ni) {
                int row = wn * FN * 16 + ni * 16 + lr;
                int off = row * 128 + ((((ks << 2) | kg) ^ (row & 7)) << 4);
                bh[ni] = *(const short8*)(sBhi + off);
                bl[ni] = *(const short8*)(sBlo + off);
            }
            #pragma unroll
            for (int mi = 0; mi < FM; ++mi)
                #pragma unroll
                for (int ni = 0; ni < FN; ++ni) {
                    acc[mi][ni] = __builtin_amdgcn_mfma_f32_16x16x32_bf16(ah[mi], bh[ni], acc[mi][ni], 0, 0, 0);
                    acc[mi][ni] = __builtin_amdgcn_mfma_f32_16x16x32_bf16(ah[mi], bl[ni], acc[mi][ni], 0, 0, 0);
                    acc[mi][ni] = __builtin_amdgcn_mfma_f32_16x16x32_bf16(al[mi], bh[ni], acc[mi][ni], 0, 0, 0);
                }
        }
        __syncthreads();
    }

    #pragma unroll
    for (int mi = 0; mi < FM; ++mi)
        #pragma unroll
        for (int ni = 0; ni < FN; ++ni) {
            int col = n0 + wn * FN * 16 + ni * 16 + lr;
            #pragma unroll
            for (int r = 0; r < 4; ++r) {
                int row = m0 + wm * FM * 16 + mi * 16 + kg * 4 + r;
                C[(size_t)row * ldc + col] = acc[mi][ni][r];
            }
        }
}

// ---------- block reduce (sum, sumsq) over 256 threads ----------
__device__ inline void block_reduce2(float& s, float& sq, int tid) {
    #pragma unroll
    for (int off = 32; off > 0; off >>= 1) { s += __shfl_down(s, off); sq += __shfl_down(sq, off); }
    __shared__ float rs[4], rq[4];
    if ((tid & 63) == 0) { rs[tid >> 6] = s; rq[tid >> 6] = sq; }
    __syncthreads();
    s  = rs[0] + rs[1] + rs[2] + rs[3];
    sq = rq[0] + rq[1] + rq[2] + rq[3];
}

// ---------- LN over S1 rows of 3072 (adds bias first), in place, gamma0/beta0 ----------
__global__ __launch_bounds__(256)
void ln_rows_v(float* __restrict__ S1, const float* __restrict__ bias,
               const float* __restrict__ gammas, const float* __restrict__ betas)
{
    const int row = blockIdx.x, tid = threadIdx.x;
    float* p = S1 + (size_t)row * INNER;
    float a[12];
    float s = 0.f, sq = 0.f;
    #pragma unroll
    for (int i = 0; i < 3; ++i) {
        int c = tid + i * 256;
        float4 v = *(const float4*)(p + c * 4);
        float4 bb = *(const float4*)(bias + c * 4);
        a[i*4+0] = v.x + bb.x; a[i*4+1] = v.y + bb.y; a[i*4+2] = v.z + bb.z; a[i*4+3] = v.w + bb.w;
        s += a[i*4+0] + a[i*4+1] + a[i*4+2] + a[i*4+3];
        sq += a[i*4+0]*a[i*4+0] + a[i*4+1]*a[i*4+1] + a[i*4+2]*a[i*4+2] + a[i*4+3]*a[i*4+3];
    }
    block_reduce2(s, sq, tid);
    const float mean = s / (float)INNER;
    const float var  = sq / (float)INNER - mean * mean;
    const float denom = sqrtf(var + EPSF) + EPSF;
    #pragma unroll
    for (int i = 0; i < 3; ++i) {
        int c = tid + i * 256;
        float4 o;
        o.x = gammas[c*4+0] * (a[i*4+0] - mean) / denom + betas[c*4+0];
        o.y = gammas[c*4+1] * (a[i*4+1] - mean) / denom + betas[c*4+1];
        o.z = gammas[c*4+2] * (a[i*4+2] - mean) / denom + betas[c*4+2];
        o.w = gammas[c*4+3] * (a[i*4+3] - mean) / denom + betas[c*4+3];
        *(float4*)(p + c * 4) = o;
    }
}

// ---------- step elementwise 1: LN(s2raw, 2048) -> z fp32, rh split bf16 ----------
__global__ __launch_bounds__(256)
void step_e1_v(const float* __restrict__ s2raw, const float* __restrict__ S1,
               const float* __restrict__ h,
               const float* __restrict__ gammas, const float* __restrict__ betas,
               float* __restrict__ z, u16* __restrict__ rh_hi, u16* __restrict__ rh_lo, int t)
{
    const int b = blockIdx.x, tid = threadIdx.x;
    const float* row = s2raw + (size_t)b * NZ;
    float az[4], ar[4];
    {
        float4 vz = *(const float4*)(row + tid * 4);
        float4 vr = *(const float4*)(row + 1024 + tid * 4);
        az[0]=vz.x; az[1]=vz.y; az[2]=vz.z; az[3]=vz.w;
        ar[0]=vr.x; ar[1]=vr.y; ar[2]=vr.z; ar[3]=vr.w;
    }
    float s = 0.f, sq = 0.f;
    #pragma unroll
    for (int q = 0; q < 4; ++q) { s += az[q] + ar[q]; sq += az[q]*az[q] + ar[q]*ar[q]; }
    block_reduce2(s, sq, tid);
    const float mean = s / (float)NZ;
    const float var  = sq / (float)NZ - mean * mean;
    const float denom = sqrtf(var + EPSF) + EPSF;

    const float* s1 = S1 + (size_t)(b * T + t) * INNER;
    const int j0 = tid * 4;
    float4 zo;
    float* zp = (float*)&zo;
    #pragma unroll
    for (int q = 0; q < 4; ++q) {
        int j = j0 + q;
        float ln = gammas[INNER + j] * (az[q] - mean) / denom + betas[INNER + j];
        float sv = 0.2f * (s1[j] + ln) + 0.5f;
        zp[q] = fminf(fmaxf(sv, 0.f), 1.f);
    }
    *(float4*)(z + (size_t)b * H + j0) = zo;

    uint2 hp, lp;
    u16 hh[4], ll[4];
    #pragma unroll
    for (int q = 0; q < 4; ++q) {
        int j = 1024 + j0 + q;
        float ln = gammas[INNER + j] * (ar[q] - mean) / denom + betas[INNER + j];
        float sv = 0.2f * (s1[j] + ln) + 0.5f;
        sv = fminf(fmaxf(sv, 0.f), 1.f);
        float rv = sv * h[(size_t)b * H + j0 + q];
        hh[q] = f2bf(rv);
        ll[q] = f2bf(rv - bf2f(hh[q]));
    }
    hp.x = (u32)hh[0] | ((u32)hh[1] << 16); hp.y = (u32)hh[2] | ((u32)hh[3] << 16);
    lp.x = (u32)ll[0] | ((u32)ll[1] << 16); lp.y = (u32)ll[2] | ((u32)ll[3] << 16);
    *(uint2*)(rh_hi + (size_t)b * H + j0) = hp;
    *(uint2*)(rh_lo + (size_t)b * H + j0) = lp;
}

// ---------- step elementwise 2: LN(candraw, 1024) -> tanh -> h update ----------
__global__ __launch_bounds__(256)
void step_e2_v(const float* __restrict__ candraw, const float* __restrict__ S1,
               const float* __restrict__ gammas, const float* __restrict__ betas,
               const float* __restrict__ z, float* __restrict__ h,
               u16* __restrict__ h_hi, u16* __restrict__ h_lo,
               float* __restrict__ out, int t)
{
    const int b = blockIdx.x, tid = threadIdx.x;
    float a[4];
    {
        float4 v = *(const float4*)(candraw + (size_t)b * H + tid * 4);
        a[0]=v.x; a[1]=v.y; a[2]=v.z; a[3]=v.w;
    }
    float s = a[0]+a[1]+a[2]+a[3];
    float sq = a[0]*a[0]+a[1]*a[1]+a[2]*a[2]+a[3]*a[3];
    block_reduce2(s, sq, tid);
    const float mean = s / (float)H;
    const float var  = sq / (float)H - mean * mean;
    const float denom = sqrtf(var + EPSF) + EPSF;

    const float* s1 = S1 + (size_t)(b * T + t) * INNER + NZ;
    const int j0 = tid * 4;
    float4 ho, oo;
    float* hp_ = (float*)&ho; float* op = (float*)&oo;
    u16 hh[4], ll[4];
    #pragma unroll
    for (int q = 0; q < 4; ++q) {
        int j = j0 + q;
        float ln = gammas[INNER + NZ + j] * (a[q] - mean) / denom + betas[INNER + NZ + j];
        float cand = tanhf(s1[j] + ln);
        float zz = z[(size_t)b * H + j];
        float hold = h[(size_t)b * H + j];
        float hn = zz * hold + (1.f - zz) * cand;
        hp_[q] = hn; op[q] = hn;
        hh[q] = f2bf(hn);
        ll[q] = f2bf(hn - bf2f(hh[q]));
    }
    *(float4*)(h + (size_t)b * H + j0) = ho;
    uint2 hpck, lpck;
    hpck.x = (u32)hh[0] | ((u32)hh[1] << 16); hpck.y = (u32)hh[2] | ((u32)hh[3] << 16);
    lpck.x = (u32)ll[0] | ((u32)ll[1] << 16); lpck.y = (u32)ll[2] | ((u32)ll[3] << 16);
    *(uint2*)(h_hi + (size_t)b * H + j0) = hpck;
    *(uint2*)(h_lo + (size_t)b * H + j0) = lpck;
    *(float4*)(out + ((size_t)b * T + t) * H + j0) = oo;
}

// ================= fallback (validated fp32 path) =================
__global__ __launch_bounds__(256)
void gemm_fb(const float* __restrict__ A, int lda,
             const float* __restrict__ Bm, int ldb,
             float* __restrict__ C, int ldc, int K)
{
    constexpr int BM = 64, BN = 64, BK = 16;
    __shared__ float As[BK][BM];
    __shared__ float Bs[BK][BN];
    const int tid = threadIdx.x;
    const int tx = tid & 15, ty = tid >> 4;
    float acc[4][4] = {};
    const float* Ab = A + (size_t)blockIdx.y * BM * lda;
    const float* Bb = Bm + (size_t)blockIdx.x * BN;
    for (int k0 = 0; k0 < K; k0 += BK) {
        #pragma unroll
        for (int i = 0; i < 4; ++i) {
            int e = tid + i * 256; int m = e >> 4, k = e & 15;
            As[k][m] = Ab[(size_t)m * lda + k0 + k];
        }
        #pragma unroll
        for (int i = 0; i < 4; ++i) {
            int e = tid + i * 256; int k = e >> 6, n = e & 63;
            Bs[k][n] = Bb[(size_t)(k0 + k) * ldb + n];
        }
        __syncthreads();
        #pragma unroll
        for (int k = 0; k < BK; ++k) {
            float av[4], bv[4];
            #pragma unroll
            for (int i = 0; i < 4; ++i) av[i] = As[k][ty * 4 + i];
            #pragma unroll
            for (int j = 0; j < 4; ++j) bv[j] = Bs[k][tx * 4 + j];
            #pragma unroll
            for (int i = 0; i < 4; ++i)
                #pragma unroll
                for (int j = 0; j < 4; ++j)
                    acc[i][j] = fmaf(av[i], bv[j], acc[i][j]);
        }
        __syncthreads();
    }
    const int row0 = blockIdx.y * BM + ty * 4;
    const int col0 = blockIdx.x * BN + tx * 4;
    #pragma unroll
    for (int i = 0; i < 4; ++i)
        #pragma unroll
        for (int j = 0; j < 4; ++j)
            C[(size_t)(row0 + i) * ldc + col0 + j] = acc[i][j];
}

__global__ __launch_bounds__(256)
void step_e1_fb(const float* __restrict__ s2raw, const float* __restrict__ S1,
                const float* __restrict__ h,
                const float* __restrict__ gammas, const float* __restrict__ betas,
                float* __restrict__ z, float* __restrict__ rh, int t)
{
    const int b = blockIdx.x, tid = threadIdx.x;
    const float* row = s2raw + (size_t)b * NZ;
    float v[8]; float s = 0.f, sq = 0.f;
    #pragma unroll
    for (int i = 0; i < 8; ++i) { v[i] = row[tid + i * 256]; s += v[i]; sq += v[i]*v[i]; }
    block_reduce2(s, sq, tid);
    const float mean = s / (float)NZ;
    const float var  = sq / (float)NZ - mean * mean;
    const float denom = sqrtf(var + EPSF) + EPSF;
    const float* s1 = S1 + (size_t)(b * T + t) * INNER;
    #pragma unroll
    for (int i = 0; i < 8; ++i) {
        int j = tid + i * 256;
        float ln = gammas[INNER + j] * (v[i] - mean) / denom + betas[INNER + j];
        float sv = 0.2f * (s1[j] + ln) + 0.5f;
        sv = fminf(fmaxf(sv, 0.f), 1.f);
        if (j < H) z[(size_t)b * H + j] = sv;
        else       rh[(size_t)b * H + (j - H)] = sv * h[(size_t)b * H + (j - H)];
    }
}

__global__ __launch_bounds__(256)
void step_e2_fb(const float* __restrict__ candraw, const float* __restrict__ S1,
                const float* __restrict__ gammas, const float* __restrict__ betas,
                const float* __restrict__ z, float* __restrict__ h,
                float* __restrict__ out, int t)
{
    const int b = blockIdx.x, tid = threadIdx.x;
    float v[4]; float s = 0.f, sq = 0.f;
    #pragma unroll
    for (int i = 0; i < 4; ++i) { v[i] = candraw[(size_t)b * H + tid + i * 256]; s += v[i]; sq += v[i]*v[i]; }
    block_reduce2(s, sq, tid);
    const float mean = s / (float)H;
    const float var  = sq / (float)H - mean * mean;
    const float denom = sqrtf(var + EPSF) + EPSF;
    const float* s1 = S1 + (size_t)(b * T + t) * INNER + NZ;
    #pragma unroll
    for (int i = 0; i < 4; ++i) {
        int j = tid + i * 256;
        float ln = gammas[INNER + NZ + j] * (v[i] - mean) / denom + betas[INNER + NZ + j];
        float cand = tanhf(s1[j] + ln);
        float zz = z[(size_t)b * H + j];
        float hold = h[(size_t)b * H + j];
        float hn = zz * hold + (1.f - zz) * cand;
        h[(size_t)b * H + j] = hn;
        out[((size_t)b * T + t) * H + j] = hn;
    }
}

// ================= launch =================
extern "C" void kernel_launch(void* const* d_in, const int* in_sizes, int n_in,
                              void* d_out, int out_size, void* d_ws, size_t ws_size,
                              hipStream_t stream) {
    const float* x      = (const float*)d_in[0];
    const float* W      = (const float*)d_in[1];
    const float* U      = (const float*)d_in[2];
    const float* bias   = (const float*)d_in[3];
    const float* gammas = (const float*)d_in[4];
    const float* betas  = (const float*)d_in[5];
    float* out = (float*)d_out;
    (void)in_sizes; (void)n_in; (void)out_size;

    char* ws = (char*)d_ws;
    size_t off = 0;
    auto alloc = [&](size_t bytes) { void* p = ws + off; off += (bytes + 255) & ~(size_t)255; return p; };

    const size_t sz_S1 = (size_t)BT * INNER * 4;          // 402.7 MB
    const size_t sz_T  = (size_t)INNER * H * 2;           // 6.29 MB per split half
    const size_t need_new = sz_S1 + 4 * sz_T + ((size_t)B * H * 4) * 3 + (size_t)B * NZ * 4
                          + ((size_t)B * H * 2) * 4 + 16 * 1024;   // ~435 MB

    if (ws_size >= need_new) {
        float* S1    = (float*)alloc(sz_S1);
        u16* WT_hi   = (u16*)alloc(sz_T);
        u16* WT_lo   = (u16*)alloc(sz_T);
        u16* UT_hi   = (u16*)alloc(sz_T);
        u16* UT_lo   = (u16*)alloc(sz_T);
        float* h     = (float*)alloc((size_t)B * H * 4);
        float* z     = (float*)alloc((size_t)B * H * 4);
        float* s2raw = (float*)alloc((size_t)B * NZ * 4);
        float* candraw = (float*)alloc((size_t)B * H * 4);
        u16* h_hi    = (u16*)alloc((size_t)B * H * 2);
        u16* h_lo    = (u16*)alloc((size_t)B * H * 2);
        u16* rh_hi   = (u16*)alloc((size_t)B * H * 2);
        u16* rh_lo   = (u16*)alloc((size_t)B * H * 2);

        transpose_split<<<dim3(INNER / 32, H / 32), 256, 0, stream>>>(W, WT_hi, WT_lo);
        transpose_split<<<dim3(INNER / 32, H / 32), 256, 0, stream>>>(U, UT_hi, UT_lo);

        // S1raw = x @ W  (bias added in ln_rows_v)
        gemm_mfma<128, 128, 4, 4, true><<<dim3(INNER / 128, BT / 128), 256, 0, stream>>>(
            x, nullptr, nullptr, H, WT_hi, WT_lo, H, S1, INNER, H);
        ln_rows_v<<<BT, 256, 0, stream>>>(S1, bias, gammas, betas);

        hipMemsetAsync(h,    0, (size_t)B * H * 4, stream);
        hipMemsetAsync(h_hi, 0, (size_t)B * H * 2, stream);
        hipMemsetAsync(h_lo, 0, (size_t)B * H * 2, stream);

        for (int t = 0; t < T; ++t) {
            // GEMM1: s2raw = h @ Uzr^T   (32x64 tiles -> 256 blocks, full chip)
            gemm_mfma<32, 64, 1, 2, false><<<dim3(NZ / 64, B / 32), 256, 0, stream>>>(
                nullptr, h_hi, h_lo, H, UT_hi, UT_lo, H, s2raw, NZ, H);
            step_e1_v<<<B, 256, 0, stream>>>(s2raw, S1, h, gammas, betas, z, rh_hi, rh_lo, t);
            // GEMM2: candraw = rh @ Uc^T (32x32 tiles -> 256 blocks)
            gemm_mfma<32, 32, 1, 1, false><<<dim3(H / 32, B / 32), 256, 0, stream>>>(
                nullptr, rh_hi, rh_lo, H, UT_hi + (size_t)NZ * H, UT_lo + (size_t)NZ * H, H,
                candraw, H, H);
            step_e2_v<<<B, 256, 0, stream>>>(candraw, S1, gammas, betas, z, h, h_hi, h_lo, out, t);
        }
    } else {
        // fallback: validated fp32 path
        float* S1    = (float*)alloc(sz_S1);
        float* h     = (float*)alloc((size_t)B * H * 4);
        float* z     = (float*)alloc((size_t)B * H * 4);
        float* rh    = (float*)alloc((size_t)B * H * 4);
        float* s2raw = (float*)alloc((size_t)B * NZ * 4);
        float* candraw = (float*)alloc((size_t)B * H * 4);

        hipMemsetAsync(h, 0, (size_t)B * H * 4, stream);
        gemm_fb<<<dim3(INNER / 64, BT / 64), 256, 0, stream>>>(x, H, W, INNER, S1, INNER, H);
        ln_rows_v<<<BT, 256, 0, stream>>>(S1, bias, gammas, betas);
        for (int t = 0; t < T; ++t) {
            gemm_fb<<<dim3(NZ / 64, B / 64), 256, 0, stream>>>(h, H, U, INNER, s2raw, NZ, H);
            step_e1_fb<<<B, 256, 0, stream>>>(s2raw, S1, h, gammas, betas, z, rh, t);
            gemm_fb<<<dim3(H / 64, B / 64), 256, 0, stream>>>(rh, H, U + NZ, INNER, candraw, H, H);
            step_e2_fb<<<B, 256, 0, stream>>>(candraw, S1, gammas, betas, z, h, out, t);
        }
    }
}